// Round 1
// baseline (647.122 us; speedup 1.0000x reference)
//
#include <hip/hip_runtime.h>
#include <hip/hip_bf16.h>
#include <math.h>

#define N_ROWS 4096
#define DIM 256
#define HALF_MASK 2047
#define K_SEL 128u
#define R 4
#define BLOCK 256

// order-preserving float -> uint transform (ascending uint == ascending float)
__device__ __forceinline__ unsigned fkey(float f) {
    unsigned u = __float_as_uint(f);
    return (u & 0x80000000u) ? ~u : (u | 0x80000000u);
}

// ---------------------------------------------------------------------------
// prep: L2-normalize rows, compute sq[j] = sum(fn^2), expand labels, zero out
// one wave (64 lanes) per row; 4 rows per block
// ---------------------------------------------------------------------------
__global__ void prep_kernel(const float* __restrict__ feat,
                            const int* __restrict__ labels,
                            float* __restrict__ fn,
                            float* __restrict__ sq,
                            int* __restrict__ lab,
                            float* __restrict__ out)
{
    const int row  = blockIdx.x * 4 + (threadIdx.x >> 6);
    const int lane = threadIdx.x & 63;
    const float4* f4 = (const float4*)feat;
    float4 x = f4[(size_t)row * 64 + lane];
    float ss = x.x*x.x + x.y*x.y + x.z*x.z + x.w*x.w;
    #pragma unroll
    for (int m = 1; m < 64; m <<= 1) ss += __shfl_xor(ss, m, 64);
    const float nrm = sqrtf(ss);
    float4 f;
    f.x = x.x / nrm; f.y = x.y / nrm; f.z = x.z / nrm; f.w = x.w / nrm;
    ((float4*)fn)[(size_t)row * 64 + lane] = f;
    float s2 = f.x*f.x + f.y*f.y + f.z*f.z + f.w*f.w;
    #pragma unroll
    for (int m = 1; m < 64; m <<= 1) s2 += __shfl_xor(s2, m, 64);
    if (lane == 0) {
        sq[row]  = s2;
        lab[row] = labels[row & HALF_MASK];
    }
    if (blockIdx.x == 0 && threadIdx.x == 0) out[0] = 0.0f;
}

// ---------------------------------------------------------------------------
// rowloss: one block = 4 anchor rows; thread t owns columns [16t, 16t+16)
// all per-column state (dots) lives in registers
// ---------------------------------------------------------------------------
__global__ __launch_bounds__(BLOCK, 2) void rowloss_kernel(
        const float* __restrict__ fn,
        const float* __restrict__ sq,
        const int* __restrict__ lab,
        float* __restrict__ out)
{
    __shared__ __align__(16) float fi[R][DIM];
    __shared__ unsigned int hist[256];
    __shared__ float red[256];
    __shared__ int   redi[256];
    __shared__ float s_amax[R], s_Z[R];
    __shared__ unsigned int s_sel[2];

    const int tid = threadIdx.x;
    const int i0  = blockIdx.x * R;

    // stage the 4 anchor rows into LDS
    for (int idx = tid; idx < R * DIM; idx += BLOCK)
        fi[idx >> 8][idx & 255] = fn[(size_t)(i0 + (idx >> 8)) * DIM + (idx & 255)];
    __syncthreads();

    const float4* fn4 = (const float4*)fn;
    const float4* fi4 = (const float4*)&fi[0][0];
    const int j0 = tid * 16;

    // ---- phase A: dots for 16 columns x 4 rows, fully in registers ----
    float acc[16][R];
    #pragma unroll
    for (int jj = 0; jj < 16; ++jj)
        #pragma unroll
        for (int r = 0; r < R; ++r) acc[jj][r] = 0.0f;

    for (int c = 0; c < 32; ++c) {            // 8 floats of d per chunk
        float fir[R][8];
        #pragma unroll
        for (int r = 0; r < R; ++r) {
            float4 a = fi4[r * 64 + c * 2];
            float4 b = fi4[r * 64 + c * 2 + 1];
            fir[r][0] = a.x; fir[r][1] = a.y; fir[r][2] = a.z; fir[r][3] = a.w;
            fir[r][4] = b.x; fir[r][5] = b.y; fir[r][6] = b.z; fir[r][7] = b.w;
        }
        #pragma unroll
        for (int jj = 0; jj < 16; ++jj) {
            const float4* p = fn4 + (size_t)(j0 + jj) * 64 + c * 2;
            float4 x = p[0];
            float4 y = p[1];
            #pragma unroll
            for (int r = 0; r < R; ++r) {
                float s = acc[jj][r];
                s = fmaf(x.x, fir[r][0], s); s = fmaf(x.y, fir[r][1], s);
                s = fmaf(x.z, fir[r][2], s); s = fmaf(x.w, fir[r][3], s);
                s = fmaf(y.x, fir[r][4], s); s = fmaf(y.y, fir[r][5], s);
                s = fmaf(y.z, fir[r][6], s); s = fmaf(y.w, fir[r][7], s);
                acc[jj][r] = s;
            }
        }
    }

    // per-thread sq chunk
    float sqr[16];
    #pragma unroll
    for (int k = 0; k < 16; ++k) sqr[k] = sq[j0 + k];

    // ---- row max (includes diagonal, matching reference) ----
    float lm[R] = {-3.4e38f, -3.4e38f, -3.4e38f, -3.4e38f};
    #pragma unroll
    for (int jj = 0; jj < 16; ++jj)
        #pragma unroll
        for (int r = 0; r < R; ++r) lm[r] = fmaxf(lm[r], acc[jj][r]);

    for (int r = 0; r < R; ++r) {
        red[tid] = lm[r]; __syncthreads();
        for (int s = 128; s > 0; s >>= 1) {
            if (tid < s) red[tid] = fmaxf(red[tid], red[tid + s]);
            __syncthreads();
        }
        if (tid == 0) s_amax[r] = 10.0f * red[0];
        __syncthreads();
    }

    // ---- Z = sum_{j != i} exp(10*dot - amax) ----
    for (int r = 0; r < R; ++r) {
        const int ir = i0 + r;
        const float am = s_amax[r];
        float z = 0.0f;
        #pragma unroll
        for (int k = 0; k < 16; ++k) {
            const int j = j0 + k;
            if (j == ir) continue;
            z += expf(fmaf(10.0f, acc[k][r], -am));
        }
        red[tid] = z; __syncthreads();
        for (int s = 128; s > 0; s >>= 1) {
            if (tid < s) red[tid] += red[tid + s];
            __syncthreads();
        }
        if (tid == 0) s_Z[r] = red[0];
        __syncthreads();
    }

    // ---- per-row: radix-select 128th largest key, then accumulate ----
    for (int r = 0; r < R; ++r) {
        const int ir = i0 + r;

        unsigned K = K_SEL, prefix = 0;
        for (int pass = 0; pass < 4; ++pass) {
            const int shift = 24 - 8 * pass;
            hist[tid] = 0; __syncthreads();
            #pragma unroll
            for (int k = 0; k < 16; ++k) {
                const unsigned u = fkey(fmaf(-2.0f, acc[k][r], sqr[k]));
                const bool act = (pass == 0) ||
                                 ((u >> (shift + 8)) == (prefix >> (shift + 8)));
                if (act) atomicAdd(&hist[(u >> shift) & 255u], 1u);
            }
            __syncthreads();
            // suffix sum: hist[v] = count of active elements with byte >= v
            for (int d = 1; d < 256; d <<= 1) {
                const unsigned o = (tid + d < 256) ? hist[tid + d] : 0u;
                __syncthreads();
                hist[tid] += o;
                __syncthreads();
            }
            const unsigned Sv = hist[tid];
            const unsigned Sn = (tid < 255) ? hist[tid + 1] : 0u;
            if (Sv >= K && Sn < K) {
                s_sel[0] = prefix | ((unsigned)tid << shift);
                s_sel[1] = K - Sn;
            }
            __syncthreads();
            prefix = s_sel[0];
            K      = s_sel[1];
            __syncthreads();
        }
        const unsigned T = prefix;
        const int needed = (int)K;   // # of ties (== T) to take, lowest index first

        // index-ordered tie ranks via block prefix scan over per-thread counts
        int tiec = 0;
        #pragma unroll
        for (int k = 0; k < 16; ++k)
            if (fkey(fmaf(-2.0f, acc[k][r], sqr[k])) == T) tiec++;
        redi[tid] = tiec; __syncthreads();
        for (int d = 1; d < 256; d <<= 1) {
            const int o = (tid >= d) ? redi[tid - d] : 0;
            __syncthreads();
            redi[tid] += o;
            __syncthreads();
        }
        int tb = redi[tid] - tiec;   // exclusive prefix of tie count
        __syncthreads();

        // accumulate over selected & same-class
        const int my = lab[ir];
        const float am = s_amax[r];
        float sd = 0.0f; int cnt = 0;
        #pragma unroll
        for (int k = 0; k < 16; ++k) {
            const int j = j0 + k;
            const unsigned u = fkey(fmaf(-2.0f, acc[k][r], sqr[k]));
            bool sel = false;
            if (u > T) sel = true;
            else if (u == T) { sel = (tb < needed); tb++; }
            if (sel && j != ir && lab[j] == my) { cnt++; sd += acc[k][r]; }
        }
        red[tid] = sd; redi[tid] = cnt; __syncthreads();
        for (int s = 128; s > 0; s >>= 1) {
            if (tid < s) { red[tid] += red[tid + s]; redi[tid] += redi[tid + s]; }
            __syncthreads();
        }
        if (tid == 0) {
            const int c = redi[0];
            if (c > 0) {
                const float lz = logf(s_Z[r]);
                const float mlpp = (10.0f * red[0] - (float)c * (am + lz)) / (float)c;
                atomicAdd(out, (-(0.1f / 0.07f) * mlpp) * (1.0f / (float)N_ROWS));
            }
        }
        __syncthreads();
    }
}

extern "C" void kernel_launch(void* const* d_in, const int* in_sizes, int n_in,
                              void* d_out, int out_size, void* d_ws, size_t ws_size,
                              hipStream_t stream) {
    (void)in_sizes; (void)n_in; (void)out_size; (void)ws_size;
    const float* feat  = (const float*)d_in[0];
    const int* labels  = (const int*)d_in[1];
    float* out = (float*)d_out;

    float* fn = (float*)d_ws;                       // N*D floats = 4 MB
    float* sq = fn + (size_t)N_ROWS * DIM;          // N floats
    int* lab  = (int*)(sq + N_ROWS);                // N ints

    prep_kernel<<<N_ROWS / 4, BLOCK, 0, stream>>>(feat, labels, fn, sq, lab, out);
    rowloss_kernel<<<N_ROWS / R, BLOCK, 0, stream>>>(fn, sq, lab, out);
}